// Round 3
// baseline (352.484 us; speedup 1.0000x reference)
//
#include <hip/hip_runtime.h>
#include <math.h>

#define TPB 256
constexpr int Bn = 64;
constexpr int Ln = 262144;          // 2^18
constexpr int S  = 4096;            // chunk/tile size
constexpr int NC = Ln / S;          // 64 chunks per row (== wave width!)
constexpr int HA = S + 301;         // halo'd extent (4397)
constexpr int EPT = 18;             // ceil(HA/TPB)
constexpr int HAP = EPT * TPB;      // 4608 padded
constexpr int OPT = S / TPB;        // 16 outputs per thread

constexpr float TWO_PI_F = 6.28318530717958647692f;
constexpr float PI_F = 3.14159265358979323846f;
constexpr float INV_TWO_PI_F = 0.15915494309189533577f;

// wrap count: k = floor((d+pi)/(2pi)), with the reference's dm==-pi & d>0 fixup.
// For |inputs| <= pi (atan2 range) with one side zero-padded, always returns 0.
__device__ __forceinline__ int wrap_k(float d) {
    float kf = floorf(__fmaf_rn(d, INV_TWO_PI_F, 0.5f));
    float dm = __fmaf_rn(-kf, TWO_PI_F, d);
    if (dm == -PI_F && d > 0.f) kf -= 1.f;
    return (int)kf;
}

__device__ __forceinline__ int wave_iscan_int(int v) {
    int lane = threadIdx.x & 63;
#pragma unroll
    for (int o = 1; o < 64; o <<= 1) {
        int u = __shfl_up(v, o, 64);
        if (lane >= o) v += u;
    }
    return v;
}

__device__ __forceinline__ int block_escan_int(int v, int* wtot) {
    int tid = threadIdx.x, wid = tid >> 6, lane = tid & 63;
    int inc = wave_iscan_int(v);
    __syncthreads();
    if (lane == 63) wtot[wid] = inc;
    __syncthreads();
    int add = 0;
#pragma unroll
    for (int w = 0; w < TPB / 64; ++w) add += (w < wid) ? wtot[w] : 0;
    return inc - v + add;   // exclusive prefix of per-thread sums
}

__device__ __forceinline__ double block_escan_double(double v, double* wtot) {
    int tid = threadIdx.x, wid = tid >> 6, lane = tid & 63;
    double inc = v;
#pragma unroll
    for (int o = 1; o < 64; o <<= 1) {
        double u = __shfl_up(inc, o, 64);
        if (lane >= o) inc += u;
    }
    __syncthreads();
    if (lane == 63) wtot[wid] = inc;
    __syncthreads();
    double add = 0.0;
#pragma unroll
    for (int w = 0; w < TPB / 64; ++w) add += (w < wid) ? wtot[w] : 0.0;
    return inc - v + add;
}

// Single-pass: unwrap (decoupled-lookback across chunks) + moving-average
// high-pass; writes filt to out, partial sums to PS.
__global__ __launch_bounds__(TPB, 4) void k_filt(const float* __restrict__ Ig,
                                                 const float* __restrict__ Qg,
                                                 unsigned long long* __restrict__ slots,
                                                 unsigned* __restrict__ ticket,
                                                 float* __restrict__ out,
                                                 double* __restrict__ PS) {
    __shared__ float spu[HAP];          // phase -> pu -> prefix(pu)
    __shared__ float smg[HAP];          // magnitude -> prefix(magnitude)
    __shared__ int iw[TPB / 64];
    __shared__ double dw[TPB / 64];
    __shared__ double rbuf[TPB / 64][4];
    __shared__ int sh_t, sh_s150, sh_s4246, sh_O;

    const int tid = threadIdx.x;
    if (tid == 0) sh_t = (int)atomicAdd(ticket, 1u);   // start-ordered virtual block id
    __syncthreads();
    const int b = sh_t >> 6, c = sh_t & (NC - 1);
    const int t0 = c * S;
    const int base = t0 - 151;
    const float* Ib = Ig + (size_t)b * Ln;
    const float* Qb = Qg + (size_t)b * Ln;

#pragma unroll
    for (int j = 0; j < EPT; ++j) {
        int li = tid + j * TPB;
        int g = base + li;
        float ph = 0.f, m = 0.f;
        if (li < HA && g >= 0 && g < Ln) {
            float iv = Ib[g], qv = Qb[g];
            m = sqrtf(__fmaf_rn(iv, iv, qv * qv));
            ph = atan2f(qv, iv);
        }
        spu[li] = ph;
        smg[li] = m;
    }
    __syncthreads();

    const int seg = tid * EPT;

    // pass 1: wrap counts once, keep phase + thread-local inclusive scan in regs.
    float ph[EPT];
    int kloc[EPT];
    {
        float prev = spu[seg > 0 ? seg - 1 : 0];   // seg==0: d=0 -> k=0
        int run = 0;
#pragma unroll
        for (int i = 0; i < EPT; ++i) {
            float cur = spu[seg + i];
            ph[i] = cur;
            run += wrap_k(cur - prev);             // pad boundaries give k=0
            kloc[i] = run;
            prev = cur;
        }
    }
    const int excl = block_escan_int(kloc[EPT - 1], iw);
    if (tid == 8)   sh_s150  = excl + kloc[6];     // tile scan at li=150  (g=t0-1)
    if (tid == 235) sh_s4246 = excl + kloc[16];    // tile scan at li=4246 (g=t0+S-1)
    __syncthreads();

    // wave 0: publish own partial, then one-shot 64-lane lookback over the row.
    if (tid < 64) {
        unsigned long long* rows = slots + ((size_t)b << 6);
        int W = sh_s4246 - sh_s150;                // wrap-count sum of this chunk
        if (tid == 0)
            __hip_atomic_store(&rows[c], (1ull << 32) | (unsigned long long)(unsigned)W,
                               __ATOMIC_RELEASE, __HIP_MEMORY_SCOPE_AGENT);
        int v = 0;
        if (c > 0) {
            const bool need = tid < c;
            unsigned long long pk;
            for (;;) {
                pk = need ? __hip_atomic_load(&rows[tid], __ATOMIC_ACQUIRE,
                                              __HIP_MEMORY_SCOPE_AGENT)
                          : (1ull << 32);
                if (__all((int)(pk >> 32) != 0)) break;
                __builtin_amdgcn_s_sleep(2);
            }
            v = need ? (int)(unsigned)pk : 0;
#pragma unroll
            for (int o = 32; o > 0; o >>= 1) v += __shfl_down(v, o, 64);
        }
        if (tid == 0) sh_O = v;                    // row-exclusive wrap offset at t0-1
    }
    __syncthreads();
    const int oc = sh_O - sh_s150;

    // pass 2: write raw pu (registers only, no LDS reads)
#pragma unroll
    for (int i = 0; i < EPT; ++i) {
        int li = seg + i;
        int g = base + li;
        float pu = 0.f;
        if (li < HA && g >= 0 && g < Ln)
            pu = ph[i] + (float)(oc + excl + kloc[i]) * TWO_PI_F;
        spu[li] = pu;
    }
    __syncthreads();

    // gather this thread's output x-values into registers BEFORE prefix overwrite
    float xp[OPT], xm[OPT];
#pragma unroll
    for (int j = 0; j < OPT; ++j) {
        int lt = tid + j * TPB + 151;
        xp[j] = spu[lt];
        xm[j] = smg[lt];
    }

    // own-segment sums for block scan
    float rp = 0.f, rm = 0.f;
#pragma unroll
    for (int i = 0; i < EPT; ++i) {
        rp += spu[seg + i];
        rm += smg[seg + i];
    }
    double ep = block_escan_double((double)rp, dw);   // barriers inside protect gathers
    double em = block_escan_double((double)rm, dw);

    // in-place inclusive prefix (own segment only)
    {
        double runp = ep, runm = em;
#pragma unroll
        for (int i = 0; i < EPT; ++i) {
            int li = seg + i;
            runp += (double)spu[li];
            spu[li] = (float)runp;
            runm += (double)smg[li];
            smg[li] = (float)runm;
        }
    }
    __syncthreads();

    float s1mf = 0.f, s2mf = 0.f, s1pf = 0.f, s2pf = 0.f;
    float* om = out + ((size_t)b * 2) * Ln + t0;
    float* op = out + ((size_t)b * 2 + 1) * Ln + t0;
    constexpr float INV_K = 1.0f / 301.0f;
#pragma unroll
    for (int j = 0; j < OPT; ++j) {
        int t = tid + j * TPB;
        int lt = t + 151;
        float am = (smg[lt + 150] - smg[lt - 151]) * INV_K;
        float fm = xm[j] - am;
        float ap = (spu[lt + 150] - spu[lt - 151]) * INV_K;
        float fp = xp[j] - ap;
        om[t] = fm;
        op[t] = fp;
        s1mf += fm; s2mf = __fmaf_rn(fm, fm, s2mf);
        s1pf += fp; s2pf = __fmaf_rn(fp, fp, s2pf);
    }
    double a0 = (double)s1mf, a1 = (double)s2mf, a2 = (double)s1pf, a3 = (double)s2pf;
    int lane = tid & 63, wid = tid >> 6;
#pragma unroll
    for (int o = 32; o > 0; o >>= 1) {
        a0 += __shfl_down(a0, o, 64);
        a1 += __shfl_down(a1, o, 64);
        a2 += __shfl_down(a2, o, 64);
        a3 += __shfl_down(a3, o, 64);
    }
    if (lane == 0) { rbuf[wid][0] = a0; rbuf[wid][1] = a1; rbuf[wid][2] = a2; rbuf[wid][3] = a3; }
    __syncthreads();
    if (tid == 0) {
        double t0d = 0, t1d = 0, t2d = 0, t3d = 0;
#pragma unroll
        for (int w = 0; w < TPB / 64; ++w) {
            t0d += rbuf[w][0]; t1d += rbuf[w][1]; t2d += rbuf[w][2]; t3d += rbuf[w][3];
        }
        double* p = PS + (size_t)(b * NC + c) * 4;
        p[0] = t0d; p[1] = t1d; p[2] = t2d; p[3] = t3d;
    }
}

// per-row stats
__global__ void k_stats(const double* __restrict__ PS, float* __restrict__ ROW) {
    int b = blockIdx.x;
    const double* p = PS + (size_t)(b * NC + threadIdx.x) * 4;
    double a0 = p[0], a1 = p[1], a2 = p[2], a3 = p[3];
#pragma unroll
    for (int o = 32; o > 0; o >>= 1) {
        a0 += __shfl_down(a0, o, 64);
        a1 += __shfl_down(a1, o, 64);
        a2 += __shfl_down(a2, o, 64);
        a3 += __shfl_down(a3, o, 64);
    }
    if (threadIdx.x == 0) {
        double Ld = (double)Ln;
        double mm = a0 / Ld;
        double vm = (a1 - a0 * a0 / Ld) / (Ld - 1.0); vm = vm > 0 ? vm : 0;
        double mp = a2 / Ld;
        double vp = (a3 - a2 * a2 / Ld) / (Ld - 1.0); vp = vp > 0 ? vp : 0;
        float* r = ROW + b * 4;
        r[0] = (float)mm;
        r[1] = (float)(1.0 / (sqrt(vm) + 1e-5));
        r[2] = (float)mp;
        r[3] = (float)(1.0 / (sqrt(vp) + 1e-5));
    }
}

// in-place normalize of d_out
__global__ __launch_bounds__(TPB) void k_norm(float* __restrict__ out,
                                              const float* __restrict__ ROW) {
    const size_t n4 = (size_t)Bn * 2 * Ln / 4;
    size_t stride = (size_t)gridDim.x * blockDim.x;
    for (size_t p4 = (size_t)blockIdx.x * blockDim.x + threadIdx.x; p4 < n4; p4 += stride) {
        size_t p = p4 * 4;
        int b = (int)(p >> 19);             // 2L = 2^19
        int sig = (int)((p >> 18) & 1);     // L = 2^18
        float mean = ROW[b * 4 + sig * 2];
        float scale = ROW[b * 4 + sig * 2 + 1];
        float4 v = reinterpret_cast<float4*>(out)[p4];
        v.x = (v.x - mean) * scale;
        v.y = (v.y - mean) * scale;
        v.z = (v.z - mean) * scale;
        v.w = (v.w - mean) * scale;
        reinterpret_cast<float4*>(out)[p4] = v;
    }
}

extern "C" void kernel_launch(void* const* d_in, const int* in_sizes, int n_in,
                              void* d_out, int out_size, void* d_ws, size_t ws_size,
                              hipStream_t stream) {
    const float* Ig = (const float*)d_in[0];
    const float* Qg = (const float*)d_in[1];
    float* out = (float*)d_out;
    char* ws = (char*)d_ws;
    unsigned long long* slots = (unsigned long long*)ws;    // Bn*NC u64 = 32 KiB
    unsigned* ticket = (unsigned*)(ws + 32768);             // 4 B (padded to 64)
    double* PS = (double*)(ws + 32832);                     // Bn*NC*4 doubles (128 KiB)
    float* ROW = (float*)(ws + 32832 + (size_t)Bn * NC * 4 * sizeof(double));

    // lookback flags + ticket counter must be zero at kernel start, every launch
    hipMemsetAsync(ws, 0, 32832, stream);
    hipLaunchKernelGGL(k_filt, dim3(Bn * NC), dim3(TPB), 0, stream,
                       Ig, Qg, slots, ticket, out, PS);
    hipLaunchKernelGGL(k_stats, dim3(Bn), dim3(64), 0, stream, PS, ROW);
    hipLaunchKernelGGL(k_norm, dim3(2048), dim3(TPB), 0, stream, out, ROW);
}

// Round 4
// 129.432 us; speedup vs baseline: 2.7233x; 2.7233x over previous
//
#include <hip/hip_runtime.h>
#include <math.h>

#define TPB 256
constexpr int Bn = 64;
constexpr int Ln = 262144;          // 2^18
constexpr int S  = 4096;            // chunk/tile size
constexpr int NC = Ln / S;          // 64 chunks per row
constexpr int HA = S + 301;         // halo'd extent (4397)
constexpr int EPT = 18;             // ceil(HA/TPB)
constexpr int HAP = EPT * TPB;      // 4608 padded
constexpr int OPT = S / TPB;        // 16 outputs per thread

constexpr float TWO_PI_F = 6.28318530717958647692f;
constexpr float PI_F = 3.14159265358979323846f;
constexpr float HALF_PI_F = 1.57079632679489661923f;
constexpr float INV_TWO_PI_F = 0.15915494309189533577f;

// wrap count: k = floor((d+pi)/(2pi)), with the reference's dm==-pi & d>0 fixup.
// For |inputs| <= pi (atan2 range) with one side zero-padded, always returns 0.
__device__ __forceinline__ int wrap_k(float d) {
    float kf = floorf(__fmaf_rn(d, INV_TWO_PI_F, 0.5f));
    float dm = __fmaf_rn(-kf, TWO_PI_F, d);
    if (dm == -PI_F && d > 0.f) kf -= 1.f;
    return (int)kf;
}

// polynomial atan2, abs err ~2e-7 rad (A&S 4.4.49 deg-17 minimax on [0,1])
__device__ __forceinline__ float fast_atan2f(float q, float i) {
    float aq = fabsf(q), ai = fabsf(i);
    float mx = fmaxf(aq, ai), mn = fminf(aq, ai);
    float r = __builtin_amdgcn_rcpf(mx);
    r = r * (2.0f - mx * r);                 // one NR step
    float t = mn * r;                        // in [0, 1+eps]
    if (mx == 0.f) t = 0.f;                  // atan2(0,0) -> 0 (ref nan_to_num)
    float s = t * t;
    float p = __fmaf_rn(s, 0.0028662257f, -0.0161657367f);
    p = __fmaf_rn(p, s,  0.0429096138f);
    p = __fmaf_rn(p, s, -0.0752896400f);
    p = __fmaf_rn(p, s,  0.1065626393f);
    p = __fmaf_rn(p, s, -0.1420889944f);
    p = __fmaf_rn(p, s,  0.1999355085f);
    p = __fmaf_rn(p, s, -0.3333314528f);
    float at = __fmaf_rn(p * s, t, t);       // t + t*s*poly
    if (aq > ai) at = HALF_PI_F - at;
    if (i < 0.f) at = PI_F - at;
    return (q < 0.f) ? -at : at;
}

__device__ __forceinline__ int wave_iscan_int(int v) {
    int lane = threadIdx.x & 63;
#pragma unroll
    for (int o = 1; o < 64; o <<= 1) {
        int u = __shfl_up(v, o, 64);
        if (lane >= o) v += u;
    }
    return v;
}

__device__ __forceinline__ int block_escan_int(int v, int* wtot) {
    int tid = threadIdx.x, wid = tid >> 6, lane = tid & 63;
    int inc = wave_iscan_int(v);
    __syncthreads();
    if (lane == 63) wtot[wid] = inc;
    __syncthreads();
    int add = 0;
#pragma unroll
    for (int w = 0; w < TPB / 64; ++w) add += (w < wid) ? wtot[w] : 0;
    return inc - v + add;   // exclusive prefix of per-thread sums
}

__device__ __forceinline__ double block_escan_double(double v, double* wtot) {
    int tid = threadIdx.x, wid = tid >> 6, lane = tid & 63;
    double inc = v;
#pragma unroll
    for (int o = 1; o < 64; o <<= 1) {
        double u = __shfl_up(inc, o, 64);
        if (lane >= o) inc += u;
    }
    __syncthreads();
    if (lane == 63) wtot[wid] = inc;
    __syncthreads();
    double add = 0.0;
#pragma unroll
    for (int w = 0; w < TPB / 64; ++w) add += (w < wid) ? wtot[w] : 0.0;
    return inc - v + add;
}

// K1: LOCALLY-anchored unwrap + moving-average high-pass (shift-invariance of
// x - avg makes the cross-chunk 2*pi offset cancel everywhere except windows
// touching zero-pads; row start is naturally exact, row end fixed by k_fix).
// Publishes local scan values at li=150 / li=4246 for k_fix.
__global__ __launch_bounds__(TPB, 4) void k_filt(const float* __restrict__ Ig,
                                                 const float* __restrict__ Qg,
                                                 int* __restrict__ Ag,     // scan at li=150
                                                 int* __restrict__ Bg,     // scan at li=4246
                                                 float* __restrict__ out,
                                                 double* __restrict__ PS) {
    __shared__ float spu[HAP];          // phase -> pu -> prefix(pu)
    __shared__ float smg[HAP];          // magnitude -> prefix(magnitude)
    __shared__ int iw[TPB / 64];
    __shared__ double dw[TPB / 64];
    __shared__ double rbuf[TPB / 64][4];

    const int c = blockIdx.x, b = blockIdx.y;
    const int t0 = c * S;
    const int base = t0 - 151;
    const int tid = threadIdx.x;
    const float* Ib = Ig + (size_t)b * Ln;
    const float* Qb = Qg + (size_t)b * Ln;

#pragma unroll
    for (int j = 0; j < EPT; ++j) {
        int li = tid + j * TPB;
        int g = base + li;
        float ph = 0.f, m = 0.f;
        if (li < HA && g >= 0 && g < Ln) {
            float iv = Ib[g], qv = Qb[g];
            m = sqrtf(__fmaf_rn(iv, iv, qv * qv));
            ph = fast_atan2f(qv, iv);
        }
        spu[li] = ph;
        smg[li] = m;
    }
    __syncthreads();

    const int seg = tid * EPT;
    const float prev0 = (seg > 0) ? spu[seg - 1] : 0.f;

    // pass 1: per-thread wrap-count sum (+ capture scan at li==150 / li==4246)
    int run = 0, my150 = 0, my4246 = 0;
    {
        float prev = prev0;
#pragma unroll
        for (int i = 0; i < EPT; ++i) {
            int li = seg + i;
            float cur = spu[li];
            int k = 0;
            if (li >= 1 && li < HA) k = wrap_k(cur - prev);  // pads give k=0
            run += k;
            if (li == 150) my150 = run;
            if (li == 4246) my4246 = run;
            prev = cur;
        }
    }
    const int excl = block_escan_int(run, iw);
    if (tid == 8)   Ag[b * NC + c] = excl + my150;    // local scan at g=t0-1
    if (tid == 235) Bg[b * NC + c] = excl + my4246;   // local scan at g=t0+S-1

    // pass 2: recompute wrap counts, write locally-anchored pu in place
    {
        float prev = prev0;
        int r2 = 0;
#pragma unroll
        for (int i = 0; i < EPT; ++i) {
            int li = seg + i;
            int g = base + li;
            float cur = spu[li];
            int k = 0;
            if (li >= 1 && li < HA) k = wrap_k(cur - prev);
            r2 += k;
            float pu = 0.f;
            if (li < HA && g >= 0 && g < Ln)
                pu = cur + (float)(excl + r2) * TWO_PI_F;
            spu[li] = pu;
            prev = cur;
        }
    }
    __syncthreads();

    // gather this thread's output x-values into registers BEFORE prefix overwrite
    float xp[OPT], xm[OPT];
#pragma unroll
    for (int j = 0; j < OPT; ++j) {
        int lt = tid + j * TPB + 151;
        xp[j] = spu[lt];
        xm[j] = smg[lt];
    }

    // own-segment sums for block scan
    float rp = 0.f, rm = 0.f;
#pragma unroll
    for (int i = 0; i < EPT; ++i) {
        rp += spu[seg + i];
        rm += smg[seg + i];
    }
    double ep = block_escan_double((double)rp, dw);   // barriers inside protect gathers
    double em = block_escan_double((double)rm, dw);

    // in-place inclusive prefix (own segment only)
    {
        double runp = ep, runm = em;
#pragma unroll
        for (int i = 0; i < EPT; ++i) {
            int li = seg + i;
            runp += (double)spu[li];
            spu[li] = (float)runp;
            runm += (double)smg[li];
            smg[li] = (float)runm;
        }
    }
    __syncthreads();

    float s1mf = 0.f, s2mf = 0.f, s1pf = 0.f, s2pf = 0.f;
    float* om = out + ((size_t)b * 2) * Ln + t0;
    float* op = out + ((size_t)b * 2 + 1) * Ln + t0;
    constexpr float INV_K = 1.0f / 301.0f;
#pragma unroll
    for (int j = 0; j < OPT; ++j) {
        int t = tid + j * TPB;
        int lt = t + 151;
        float am = (smg[lt + 150] - smg[lt - 151]) * INV_K;
        float fm = xm[j] - am;
        float ap = (spu[lt + 150] - spu[lt - 151]) * INV_K;
        float fp = xp[j] - ap;
        om[t] = fm;
        op[t] = fp;
        s1mf += fm; s2mf = __fmaf_rn(fm, fm, s2mf);
        s1pf += fp; s2pf = __fmaf_rn(fp, fp, s2pf);
    }
    double a0 = (double)s1mf, a1 = (double)s2mf, a2 = (double)s1pf, a3 = (double)s2pf;
    int lane = tid & 63, wid = tid >> 6;
#pragma unroll
    for (int o = 32; o > 0; o >>= 1) {
        a0 += __shfl_down(a0, o, 64);
        a1 += __shfl_down(a1, o, 64);
        a2 += __shfl_down(a2, o, 64);
        a3 += __shfl_down(a3, o, 64);
    }
    if (lane == 0) { rbuf[wid][0] = a0; rbuf[wid][1] = a1; rbuf[wid][2] = a2; rbuf[wid][3] = a3; }
    __syncthreads();
    if (tid == 0) {
        double t0d = 0, t1d = 0, t2d = 0, t3d = 0;
#pragma unroll
        for (int w = 0; w < TPB / 64; ++w) {
            t0d += rbuf[w][0]; t1d += rbuf[w][1]; t2d += rbuf[w][2]; t3d += rbuf[w][3];
        }
        double* p = PS + (size_t)(b * NC + c) * 4;
        p[0] = t0d; p[1] = t1d; p[2] = t2d; p[3] = t3d;
    }
}

// K2: per-row fixup of the last 150 phase outputs (windows touching right pad)
// and the corresponding chunk-63 phase partial sums. One wave per row.
__global__ void k_fix(const int* __restrict__ Ag, const int* __restrict__ Bg,
                      float* __restrict__ out, double* __restrict__ PS) {
    const int b = blockIdx.x;
    const int lane = threadIdx.x;           // 64 threads
    int a = Ag[b * NC + lane];
    int bb = Bg[b * NC + lane];
    int a63 = __shfl(a, 63, 64);
    int w = (lane < 63) ? (bb - a) : 0;     // chunk wrap sums W_c
#pragma unroll
    for (int o = 32; o > 0; o >>= 1) w += __shfl_down(w, o, 64);
    int O63 = __shfl(w, 0, 64);             // row wrap offset at chunk 63 start
    float C = TWO_PI_F * (float)(O63 - a63);  // pu_true - pu_prov for chunk 63

    constexpr float INV_K = 1.0f / 301.0f;
    float* op = out + ((size_t)b * 2 + 1) * Ln;
    double sd = 0.0, sd2 = 0.0;
#pragma unroll
    for (int k = 0; k < 3; ++k) {
        int j = lane + k * 64;
        if (j < 150) {
            int t = Ln - 150 + j;           // npad in window = j+1
            float delta = C * (float)(j + 1) * INV_K;
            float v = op[t];
            float nv = v + delta;
            op[t] = nv;
            sd += (double)delta;
            sd2 += (double)nv * (double)nv - (double)v * (double)v;
        }
    }
#pragma unroll
    for (int o = 32; o > 0; o >>= 1) {
        sd += __shfl_down(sd, o, 64);
        sd2 += __shfl_down(sd2, o, 64);
    }
    if (lane == 0) {
        double* p = PS + (size_t)(b * NC + 63) * 4;
        p[2] += sd;
        p[3] += sd2;
    }
}

// per-row stats
__global__ void k_stats(const double* __restrict__ PS, float* __restrict__ ROW) {
    int b = blockIdx.x;
    const double* p = PS + (size_t)(b * NC + threadIdx.x) * 4;
    double a0 = p[0], a1 = p[1], a2 = p[2], a3 = p[3];
#pragma unroll
    for (int o = 32; o > 0; o >>= 1) {
        a0 += __shfl_down(a0, o, 64);
        a1 += __shfl_down(a1, o, 64);
        a2 += __shfl_down(a2, o, 64);
        a3 += __shfl_down(a3, o, 64);
    }
    if (threadIdx.x == 0) {
        double Ld = (double)Ln;
        double mm = a0 / Ld;
        double vm = (a1 - a0 * a0 / Ld) / (Ld - 1.0); vm = vm > 0 ? vm : 0;
        double mp = a2 / Ld;
        double vp = (a3 - a2 * a2 / Ld) / (Ld - 1.0); vp = vp > 0 ? vp : 0;
        float* r = ROW + b * 4;
        r[0] = (float)mm;
        r[1] = (float)(1.0 / (sqrt(vm) + 1e-5));
        r[2] = (float)mp;
        r[3] = (float)(1.0 / (sqrt(vp) + 1e-5));
    }
}

// in-place normalize of d_out
__global__ __launch_bounds__(TPB) void k_norm(float* __restrict__ out,
                                              const float* __restrict__ ROW) {
    const size_t n4 = (size_t)Bn * 2 * Ln / 4;
    size_t stride = (size_t)gridDim.x * blockDim.x;
    for (size_t p4 = (size_t)blockIdx.x * blockDim.x + threadIdx.x; p4 < n4; p4 += stride) {
        size_t p = p4 * 4;
        int b = (int)(p >> 19);             // 2L = 2^19
        int sig = (int)((p >> 18) & 1);     // L = 2^18
        float mean = ROW[b * 4 + sig * 2];
        float scale = ROW[b * 4 + sig * 2 + 1];
        float4 v = reinterpret_cast<float4*>(out)[p4];
        v.x = (v.x - mean) * scale;
        v.y = (v.y - mean) * scale;
        v.z = (v.z - mean) * scale;
        v.w = (v.w - mean) * scale;
        reinterpret_cast<float4*>(out)[p4] = v;
    }
}

extern "C" void kernel_launch(void* const* d_in, const int* in_sizes, int n_in,
                              void* d_out, int out_size, void* d_ws, size_t ws_size,
                              hipStream_t stream) {
    const float* Ig = (const float*)d_in[0];
    const float* Qg = (const float*)d_in[1];
    float* out = (float*)d_out;
    char* ws = (char*)d_ws;
    int* Ag = (int*)ws;                                     // Bn*NC ints (16 KiB)
    int* Bg = (int*)(ws + 16384);                           // Bn*NC ints (16 KiB)
    double* PS = (double*)(ws + 32768);                     // Bn*NC*4 doubles (128 KiB)
    float* ROW = (float*)(ws + 32768 + (size_t)Bn * NC * 4 * sizeof(double));

    dim3 grid(NC, Bn);
    hipLaunchKernelGGL(k_filt, grid, dim3(TPB), 0, stream, Ig, Qg, Ag, Bg, out, PS);
    hipLaunchKernelGGL(k_fix, dim3(Bn), dim3(64), 0, stream, Ag, Bg, out, PS);
    hipLaunchKernelGGL(k_stats, dim3(Bn), dim3(64), 0, stream, PS, ROW);
    hipLaunchKernelGGL(k_norm, dim3(2048), dim3(TPB), 0, stream, out, ROW);
}

// Round 5
// 118.670 us; speedup vs baseline: 2.9703x; 1.0907x over previous
//
#include <hip/hip_runtime.h>
#include <math.h>

#define TPB 256
constexpr int Bn = 64;
constexpr int Ln = 262144;          // 2^18
constexpr int S  = 4096;            // chunk/tile size
constexpr int NC = Ln / S;          // 64 chunks per row
constexpr int HA = S + 301;         // halo'd extent (4397)
constexpr int EPT = 18;             // ceil(HA/TPB)
constexpr int HAP = EPT * TPB;      // 4608 logical extent
constexpr int OPT = S / TPB;        // 16 outputs per thread
constexpr int A4 = 4400;            // aligned vector window (floats), covers [base-1, base+4399)
constexpr int NV4 = A4 / 4;         // 1100 float4s
constexpr int LDSZ = 4624;          // HAP + 1 (shift) + pad

constexpr float TWO_PI_F = 6.28318530717958647692f;
constexpr float PI_F = 3.14159265358979323846f;
constexpr float HALF_PI_F = 1.57079632679489661923f;
constexpr float INV_TWO_PI_F = 0.15915494309189533577f;

// wrap count: k = floor((d+pi)/(2pi)), with the reference's dm==-pi & d>0 fixup.
__device__ __forceinline__ int wrap_k(float d) {
    float kf = floorf(__fmaf_rn(d, INV_TWO_PI_F, 0.5f));
    float dm = __fmaf_rn(-kf, TWO_PI_F, d);
    if (dm == -PI_F && d > 0.f) kf -= 1.f;
    return (int)kf;
}

// polynomial atan2, abs err ~2e-7 rad
__device__ __forceinline__ float fast_atan2f(float q, float i) {
    float aq = fabsf(q), ai = fabsf(i);
    float mx = fmaxf(aq, ai), mn = fminf(aq, ai);
    float r = __builtin_amdgcn_rcpf(mx);
    r = r * (2.0f - mx * r);                 // one NR step
    float t = mn * r;                        // in [0, 1+eps]
    if (mx == 0.f) t = 0.f;                  // atan2(0,0) -> 0
    float s = t * t;
    float p = __fmaf_rn(s, 0.0028662257f, -0.0161657367f);
    p = __fmaf_rn(p, s,  0.0429096138f);
    p = __fmaf_rn(p, s, -0.0752896400f);
    p = __fmaf_rn(p, s,  0.1065626393f);
    p = __fmaf_rn(p, s, -0.1420889944f);
    p = __fmaf_rn(p, s,  0.1999355085f);
    p = __fmaf_rn(p, s, -0.3333314528f);
    float at = __fmaf_rn(p * s, t, t);       // t + t*s*poly
    if (aq > ai) at = HALF_PI_F - at;
    if (i < 0.f) at = PI_F - at;
    return (q < 0.f) ? -at : at;
}

__device__ __forceinline__ int wave_iscan_int(int v) {
    int lane = threadIdx.x & 63;
#pragma unroll
    for (int o = 1; o < 64; o <<= 1) {
        int u = __shfl_up(v, o, 64);
        if (lane >= o) v += u;
    }
    return v;
}

__device__ __forceinline__ int block_escan_int(int v, int* wtot) {
    int tid = threadIdx.x, wid = tid >> 6, lane = tid & 63;
    int inc = wave_iscan_int(v);
    __syncthreads();
    if (lane == 63) wtot[wid] = inc;
    __syncthreads();
    int add = 0;
#pragma unroll
    for (int w = 0; w < TPB / 64; ++w) add += (w < wid) ? wtot[w] : 0;
    return inc - v + add;   // exclusive prefix of per-thread sums
}

__device__ __forceinline__ double block_escan_double(double v, double* wtot) {
    int tid = threadIdx.x, wid = tid >> 6, lane = tid & 63;
    double inc = v;
#pragma unroll
    for (int o = 1; o < 64; o <<= 1) {
        double u = __shfl_up(inc, o, 64);
        if (lane >= o) inc += u;
    }
    __syncthreads();
    if (lane == 63) wtot[wid] = inc;
    __syncthreads();
    double add = 0.0;
#pragma unroll
    for (int w = 0; w < TPB / 64; ++w) add += (w < wid) ? wtot[w] : 0.0;
    return inc - v + add;
}

// K1: locally-anchored unwrap + moving-average high-pass.
__global__ __launch_bounds__(TPB, 4) void k_filt(const float* __restrict__ Ig,
                                                 const float* __restrict__ Qg,
                                                 int* __restrict__ Ag,     // scan at li=150
                                                 int* __restrict__ Bg,     // scan at li=4246
                                                 float* __restrict__ out,
                                                 double* __restrict__ PS) {
    __shared__ __align__(16) float spu_s[LDSZ];   // phase -> pu -> prefix(pu)
    __shared__ __align__(16) float smg_s[LDSZ];   // magnitude -> prefix(magnitude)
    __shared__ int iw[TPB / 64];
    __shared__ double dw[TPB / 64];
    __shared__ double rbuf[TPB / 64][4];
    float* spu = spu_s + 1;             // logical li -> spu[li]
    float* smg = smg_s + 1;

    const int c = blockIdx.x, b = blockIdx.y;
    const int t0 = c * S;
    const int base = t0 - 151;
    const int tid = threadIdx.x;
    const float* Ib = Ig + (size_t)b * Ln;
    const float* Qb = Qg + (size_t)b * Ln;

    if (c > 0 && c < NC - 1) {
        // interior: fully in-range halo; aligned float4 staging
        const int astart = base - 1;    // base ≡ 1 (mod 4) -> astart 16B-aligned
        const float4* I4 = reinterpret_cast<const float4*>(Ib + astart);
        const float4* Q4 = reinterpret_cast<const float4*>(Qb + astart);
        float4 vi[5], vq[5];
#pragma unroll
        for (int j = 0; j < 5; ++j) {
            int k = tid + j * TPB;
            if (k < NV4) { vi[j] = I4[k]; vq[j] = Q4[k]; }
        }
        // zero tail while loads are in flight
        if (tid < LDSZ - A4) { spu_s[A4 + tid] = 0.f; smg_s[A4 + tid] = 0.f; }
#pragma unroll
        for (int j = 0; j < 5; ++j) {
            int k = tid + j * TPB;
            if (k < NV4) {
                float4 vp, vm;
                vm.x = sqrtf(__fmaf_rn(vi[j].x, vi[j].x, vq[j].x * vq[j].x));
                vm.y = sqrtf(__fmaf_rn(vi[j].y, vi[j].y, vq[j].y * vq[j].y));
                vm.z = sqrtf(__fmaf_rn(vi[j].z, vi[j].z, vq[j].z * vq[j].z));
                vm.w = sqrtf(__fmaf_rn(vi[j].w, vi[j].w, vq[j].w * vq[j].w));
                vp.x = fast_atan2f(vq[j].x, vi[j].x);
                vp.y = fast_atan2f(vq[j].y, vi[j].y);
                vp.z = fast_atan2f(vq[j].z, vi[j].z);
                vp.w = fast_atan2f(vq[j].w, vi[j].w);
                reinterpret_cast<float4*>(spu_s)[k] = vp;
                reinterpret_cast<float4*>(smg_s)[k] = vm;
            }
        }
    } else {
        // edge chunks (c==0, c==NC-1): guarded scalar staging, covers all li
#pragma unroll
        for (int j = 0; j < EPT; ++j) {
            int li = tid + j * TPB;
            int g = base + li;
            float ph = 0.f, m = 0.f;
            if (li < HA && g >= 0 && g < Ln) {
                float iv = Ib[g], qv = Qb[g];
                m = sqrtf(__fmaf_rn(iv, iv, qv * qv));
                ph = fast_atan2f(qv, iv);
            }
            spu[li] = ph;
            smg[li] = m;
        }
    }
    __syncthreads();

    const int seg = tid * EPT;

    // single wrap pass: phase + local inclusive wrap scan kept in registers
    float ph[EPT];
    int kloc[EPT];
    {
        float prev = (seg > 0) ? spu[seg - 1] : 0.f;
        int run = 0;
#pragma unroll
        for (int i = 0; i < EPT; ++i) {
            float cur = spu[seg + i];
            ph[i] = cur;
            int k = wrap_k(cur - prev);
            if (seg + i == 0) k = 0;      // li==0 has no predecessor
            run += k;
            kloc[i] = run;
            prev = cur;
        }
    }
    const int excl = block_escan_int(kloc[EPT - 1], iw);
    if (tid == 8)   Ag[b * NC + c] = excl + kloc[6];    // local scan at g=t0-1
    if (tid == 235) Bg[b * NC + c] = excl + kloc[16];   // local scan at g=t0+S-1

    // write locally-anchored pu from registers (own segment only; all cross-
    // thread reads of spu happened before the scan's barriers)
#pragma unroll
    for (int i = 0; i < EPT; ++i) {
        int li = seg + i;
        int g = base + li;
        float pu = 0.f;
        if (li < HA && g >= 0 && g < Ln)
            pu = ph[i] + (float)(excl + kloc[i]) * TWO_PI_F;
        spu[li] = pu;
    }
    __syncthreads();

    // gather this thread's output x-values into registers BEFORE prefix overwrite
    float xp[OPT], xm[OPT];
#pragma unroll
    for (int j = 0; j < OPT; ++j) {
        int lt = tid + j * TPB + 151;
        xp[j] = spu[lt];
        xm[j] = smg[lt];
    }

    // own-segment sums for block scan
    float rp = 0.f, rm = 0.f;
#pragma unroll
    for (int i = 0; i < EPT; ++i) {
        rp += spu[seg + i];
        rm += smg[seg + i];
    }
    double ep = block_escan_double((double)rp, dw);   // barriers inside protect gathers
    double em = block_escan_double((double)rm, dw);

    // in-place inclusive prefix (own segment only)
    {
        double runp = ep, runm = em;
#pragma unroll
        for (int i = 0; i < EPT; ++i) {
            int li = seg + i;
            runp += (double)spu[li];
            spu[li] = (float)runp;
            runm += (double)smg[li];
            smg[li] = (float)runm;
        }
    }
    __syncthreads();

    float s1mf = 0.f, s2mf = 0.f, s1pf = 0.f, s2pf = 0.f;
    float* om = out + ((size_t)b * 2) * Ln + t0;
    float* op = out + ((size_t)b * 2 + 1) * Ln + t0;
    constexpr float INV_K = 1.0f / 301.0f;
#pragma unroll
    for (int j = 0; j < OPT; ++j) {
        int t = tid + j * TPB;
        int lt = t + 151;
        float am = (smg[lt + 150] - smg[lt - 151]) * INV_K;
        float fm = xm[j] - am;
        float ap = (spu[lt + 150] - spu[lt - 151]) * INV_K;
        float fp = xp[j] - ap;
        om[t] = fm;
        op[t] = fp;
        s1mf += fm; s2mf = __fmaf_rn(fm, fm, s2mf);
        s1pf += fp; s2pf = __fmaf_rn(fp, fp, s2pf);
    }
    double a0 = (double)s1mf, a1 = (double)s2mf, a2 = (double)s1pf, a3 = (double)s2pf;
    int lane = tid & 63, wid = tid >> 6;
#pragma unroll
    for (int o = 32; o > 0; o >>= 1) {
        a0 += __shfl_down(a0, o, 64);
        a1 += __shfl_down(a1, o, 64);
        a2 += __shfl_down(a2, o, 64);
        a3 += __shfl_down(a3, o, 64);
    }
    if (lane == 0) { rbuf[wid][0] = a0; rbuf[wid][1] = a1; rbuf[wid][2] = a2; rbuf[wid][3] = a3; }
    __syncthreads();
    if (tid == 0) {
        double t0d = 0, t1d = 0, t2d = 0, t3d = 0;
#pragma unroll
        for (int w = 0; w < TPB / 64; ++w) {
            t0d += rbuf[w][0]; t1d += rbuf[w][1]; t2d += rbuf[w][2]; t3d += rbuf[w][3];
        }
        double* p = PS + (size_t)(b * NC + c) * 4;
        p[0] = t0d; p[1] = t1d; p[2] = t2d; p[3] = t3d;
    }
}

// K2: per-row fixup of the last 150 phase outputs (windows touching right pad)
__global__ void k_fix(const int* __restrict__ Ag, const int* __restrict__ Bg,
                      float* __restrict__ out, double* __restrict__ PS) {
    const int b = blockIdx.x;
    const int lane = threadIdx.x;           // 64 threads
    int a = Ag[b * NC + lane];
    int bb = Bg[b * NC + lane];
    int a63 = __shfl(a, 63, 64);
    int w = (lane < 63) ? (bb - a) : 0;     // chunk wrap sums W_c
#pragma unroll
    for (int o = 32; o > 0; o >>= 1) w += __shfl_down(w, o, 64);
    int O63 = __shfl(w, 0, 64);             // row wrap offset at chunk 63 start
    float C = TWO_PI_F * (float)(O63 - a63);  // pu_true - pu_prov for chunk 63

    constexpr float INV_K = 1.0f / 301.0f;
    float* op = out + ((size_t)b * 2 + 1) * Ln;
    double sd = 0.0, sd2 = 0.0;
#pragma unroll
    for (int k = 0; k < 3; ++k) {
        int j = lane + k * 64;
        if (j < 150) {
            int t = Ln - 150 + j;           // npad in window = j+1
            float delta = C * (float)(j + 1) * INV_K;
            float v = op[t];
            float nv = v + delta;
            op[t] = nv;
            sd += (double)delta;
            sd2 += (double)nv * (double)nv - (double)v * (double)v;
        }
    }
#pragma unroll
    for (int o = 32; o > 0; o >>= 1) {
        sd += __shfl_down(sd, o, 64);
        sd2 += __shfl_down(sd2, o, 64);
    }
    if (lane == 0) {
        double* p = PS + (size_t)(b * NC + 63) * 4;
        p[2] += sd;
        p[3] += sd2;
    }
}

// per-row stats
__global__ void k_stats(const double* __restrict__ PS, float* __restrict__ ROW) {
    int b = blockIdx.x;
    const double* p = PS + (size_t)(b * NC + threadIdx.x) * 4;
    double a0 = p[0], a1 = p[1], a2 = p[2], a3 = p[3];
#pragma unroll
    for (int o = 32; o > 0; o >>= 1) {
        a0 += __shfl_down(a0, o, 64);
        a1 += __shfl_down(a1, o, 64);
        a2 += __shfl_down(a2, o, 64);
        a3 += __shfl_down(a3, o, 64);
    }
    if (threadIdx.x == 0) {
        double Ld = (double)Ln;
        double mm = a0 / Ld;
        double vm = (a1 - a0 * a0 / Ld) / (Ld - 1.0); vm = vm > 0 ? vm : 0;
        double mp = a2 / Ld;
        double vp = (a3 - a2 * a2 / Ld) / (Ld - 1.0); vp = vp > 0 ? vp : 0;
        float* r = ROW + b * 4;
        r[0] = (float)mm;
        r[1] = (float)(1.0 / (sqrt(vm) + 1e-5));
        r[2] = (float)mp;
        r[3] = (float)(1.0 / (sqrt(vp) + 1e-5));
    }
}

// in-place normalize of d_out
__global__ __launch_bounds__(TPB) void k_norm(float* __restrict__ out,
                                              const float* __restrict__ ROW) {
    const size_t n4 = (size_t)Bn * 2 * Ln / 4;
    size_t stride = (size_t)gridDim.x * blockDim.x;
    for (size_t p4 = (size_t)blockIdx.x * blockDim.x + threadIdx.x; p4 < n4; p4 += stride) {
        size_t p = p4 * 4;
        int b = (int)(p >> 19);             // 2L = 2^19
        int sig = (int)((p >> 18) & 1);     // L = 2^18
        float mean = ROW[b * 4 + sig * 2];
        float scale = ROW[b * 4 + sig * 2 + 1];
        float4 v = reinterpret_cast<float4*>(out)[p4];
        v.x = (v.x - mean) * scale;
        v.y = (v.y - mean) * scale;
        v.z = (v.z - mean) * scale;
        v.w = (v.w - mean) * scale;
        reinterpret_cast<float4*>(out)[p4] = v;
    }
}

extern "C" void kernel_launch(void* const* d_in, const int* in_sizes, int n_in,
                              void* d_out, int out_size, void* d_ws, size_t ws_size,
                              hipStream_t stream) {
    const float* Ig = (const float*)d_in[0];
    const float* Qg = (const float*)d_in[1];
    float* out = (float*)d_out;
    char* ws = (char*)d_ws;
    int* Ag = (int*)ws;                                     // Bn*NC ints (16 KiB)
    int* Bg = (int*)(ws + 16384);                           // Bn*NC ints (16 KiB)
    double* PS = (double*)(ws + 32768);                     // Bn*NC*4 doubles (128 KiB)
    float* ROW = (float*)(ws + 32768 + (size_t)Bn * NC * 4 * sizeof(double));

    dim3 grid(NC, Bn);
    hipLaunchKernelGGL(k_filt, grid, dim3(TPB), 0, stream, Ig, Qg, Ag, Bg, out, PS);
    hipLaunchKernelGGL(k_fix, dim3(Bn), dim3(64), 0, stream, Ag, Bg, out, PS);
    hipLaunchKernelGGL(k_stats, dim3(Bn), dim3(64), 0, stream, PS, ROW);
    hipLaunchKernelGGL(k_norm, dim3(2048), dim3(TPB), 0, stream, out, ROW);
}

// Round 6
// 109.907 us; speedup vs baseline: 3.2071x; 1.0797x over previous
//
#include <hip/hip_runtime.h>
#include <math.h>

#define TPB 256
constexpr int Bn = 64;
constexpr int Ln = 262144;          // 2^18
constexpr int S  = 2048;            // chunk/tile size
constexpr int NC = Ln / S;          // 128 chunks per row
constexpr int HA = S + 301;         // halo'd extent (2349)
constexpr int EPT = 10;             // ceil(HA/TPB) -> 2560 coverage
constexpr int HAP = EPT * TPB;      // 2560 logical extent
constexpr int OPT = S / TPB;        // 8 outputs per thread
constexpr int A4 = 2352;            // staged floats (covers li in [-1, 2351))
constexpr int NP = A4 / 2;          // 1176 float2 pairs
constexpr int LDSZ = 2564;          // >= HAP + 1, zero tail

constexpr float TWO_PI_F = 6.28318530717958647692f;
constexpr float PI_F = 3.14159265358979323846f;
constexpr float HALF_PI_F = 1.57079632679489661923f;
constexpr float INV_TWO_PI_F = 0.15915494309189533577f;

// wrap count: k = floor((d+pi)/(2pi)), with the reference's dm==-pi & d>0 fixup.
// For |d| <= pi (one side zero-padded) always returns 0.
__device__ __forceinline__ int wrap_k(float d) {
    float kf = floorf(__fmaf_rn(d, INV_TWO_PI_F, 0.5f));
    float dm = __fmaf_rn(-kf, TWO_PI_F, d);
    if (dm == -PI_F && d > 0.f) kf -= 1.f;
    return (int)kf;
}

// polynomial atan2, abs err ~2e-7 rad
__device__ __forceinline__ float fast_atan2f(float q, float i) {
    float aq = fabsf(q), ai = fabsf(i);
    float mx = fmaxf(aq, ai), mn = fminf(aq, ai);
    float r = __builtin_amdgcn_rcpf(mx);
    r = r * (2.0f - mx * r);                 // one NR step
    float t = mn * r;                        // in [0, 1+eps]
    if (mx == 0.f) t = 0.f;                  // atan2(0,0) -> 0
    float s = t * t;
    float p = __fmaf_rn(s, 0.0028662257f, -0.0161657367f);
    p = __fmaf_rn(p, s,  0.0429096138f);
    p = __fmaf_rn(p, s, -0.0752896400f);
    p = __fmaf_rn(p, s,  0.1065626393f);
    p = __fmaf_rn(p, s, -0.1420889944f);
    p = __fmaf_rn(p, s,  0.1999355085f);
    p = __fmaf_rn(p, s, -0.3333314528f);
    float at = __fmaf_rn(p * s, t, t);       // t + t*s*poly
    if (aq > ai) at = HALF_PI_F - at;
    if (i < 0.f) at = PI_F - at;
    return (q < 0.f) ? -at : at;
}

// K1: locally-anchored unwrap + moving-average high-pass (2*pi row offset
// cancels in x - avg; row-end pad windows fixed by k_post).
__global__ __launch_bounds__(TPB, 6) void k_filt(const float* __restrict__ Ig,
                                                 const float* __restrict__ Qg,
                                                 int* __restrict__ Ag,     // local scan at g=t0-1
                                                 int* __restrict__ Bg,     // local scan at g=t0+S-1
                                                 float* __restrict__ out,
                                                 float* __restrict__ PS) {
    __shared__ __align__(16) float spu_s[LDSZ];   // phase -> pu -> prefix(pu)
    __shared__ __align__(16) float smg_s[LDSZ];   // magnitude -> prefix(magnitude)
    __shared__ int iwt[TPB / 64];
    __shared__ float fwt[TPB / 64];
    __shared__ double rbuf[TPB / 64][4];
    float* spu = spu_s + 1;             // logical li -> spu[li]
    float* smg = smg_s + 1;

    const int c = blockIdx.x, b = blockIdx.y;
    const int t0 = c * S;
    const int base = t0 - 151;
    const int tid = threadIdx.x;
    const int lane = tid & 63, wid = tid >> 6;
    const float* Ib = Ig + (size_t)b * Ln;
    const float* Qb = Qg + (size_t)b * Ln;

    if (c > 0 && c < NC - 1) {
        // interior: halo fully in range. float2 loads, dense b32 LDS writes
        const int astart = base - 1;    // even -> 8B-aligned float2
        const float2* I2 = reinterpret_cast<const float2*>(Ib + astart);
        const float2* Q2 = reinterpret_cast<const float2*>(Qb + astart);
        if (tid < LDSZ - A4) { spu_s[A4 + tid] = 0.f; smg_s[A4 + tid] = 0.f; }
        float2 vi[5], vq[5];
#pragma unroll
        for (int j = 0; j < 5; ++j) {
            int p = tid + j * TPB;
            if (p < NP) { vi[j] = I2[p]; vq[j] = Q2[p]; }
        }
#pragma unroll
        for (int j = 0; j < 5; ++j) {
            int p = tid + j * TPB;
            if (p < NP) {
                spu_s[2 * p]     = fast_atan2f(vq[j].x, vi[j].x);
                spu_s[2 * p + 1] = fast_atan2f(vq[j].y, vi[j].y);
                smg_s[2 * p]     = sqrtf(__fmaf_rn(vi[j].x, vi[j].x, vq[j].x * vq[j].x));
                smg_s[2 * p + 1] = sqrtf(__fmaf_rn(vi[j].y, vi[j].y, vq[j].y * vq[j].y));
            }
        }
    } else {
        // edge chunks (c==0, c==NC-1): guarded scalar staging, covers all li
#pragma unroll
        for (int j = 0; j < EPT; ++j) {
            int li = tid + j * TPB;
            int g = base + li;
            float ph = 0.f, m = 0.f;
            if (li < HA && g >= 0 && g < Ln) {
                float iv = Ib[g], qv = Qb[g];
                m = sqrtf(__fmaf_rn(iv, iv, qv * qv));
                ph = fast_atan2f(qv, iv);
            }
            spu[li] = ph;
            smg[li] = m;
        }
    }
    __syncthreads();                                   // B1

    const int seg = tid * EPT;

    // own segment -> registers; wrap scan + mg sum
    float ph[EPT], mg[EPT];
    int kloc[EPT];
    float rm = 0.f;
    {
        float prev = (seg > 0) ? spu[seg - 1] : 0.f;   // li==0: diff in (-pi,pi] -> k=0
        int run = 0;
#pragma unroll
        for (int i = 0; i < EPT; ++i) {
            ph[i] = spu[seg + i];
            mg[i] = smg[seg + i];
            run += wrap_k(ph[i] - prev);
            kloc[i] = run;
            prev = ph[i];
            rm += mg[i];
        }
    }

    // combined block exclusive scan: int wrap counts + float mg sums
    int vi_ = kloc[EPT - 1];
    float vf = rm;
#pragma unroll
    for (int o = 1; o < 64; o <<= 1) {
        int ui = __shfl_up(vi_, o, 64);
        float uf = __shfl_up(vf, o, 64);
        if (lane >= o) { vi_ += ui; vf += uf; }
    }
    __syncthreads();                                   // B2
    if (lane == 63) { iwt[wid] = vi_; fwt[wid] = vf; }
    __syncthreads();                                   // B3
    int addi = 0; float addf = 0.f;
#pragma unroll
    for (int w = 0; w < TPB / 64; ++w) {
        addi += (w < wid) ? iwt[w] : 0;
        addf += (w < wid) ? fwt[w] : 0.f;
    }
    const int excl = vi_ - kloc[EPT - 1] + addi;
    const float em = vf - rm + addf;

    if (tid == 15)  Ag[b * NC + c] = excl + kloc[0];   // li=150  (g=t0-1)
    if (tid == 219) Bg[b * NC + c] = excl + kloc[8];   // li=2198 (g=t0+S-1)

    // pu in regs; write raw pu (own segment)
    float pu[EPT];
    float rp = 0.f;
#pragma unroll
    for (int i = 0; i < EPT; ++i) {
        int li = seg + i;
        int g = base + li;
        float v = 0.f;
        if (li < HA && g >= 0 && g < Ln)
            v = ph[i] + (float)(excl + kloc[i]) * TWO_PI_F;
        pu[i] = v;
        rp += v;
        spu[li] = v;
    }

    // block exclusive scan of pu sums; x-gathers overlapped inside barrier pair
    float incf = rp;
#pragma unroll
    for (int o = 1; o < 64; o <<= 1) {
        float uf = __shfl_up(incf, o, 64);
        if (lane >= o) incf += uf;
    }
    __syncthreads();                                   // B4 (raw pu visible)
    if (lane == 63) fwt[wid] = incf;
    float xp[OPT], xm[OPT];
#pragma unroll
    for (int j = 0; j < OPT; ++j) {
        int lt = tid + j * TPB + 151;
        xp[j] = spu[lt];                               // raw pu
        xm[j] = smg[lt];                               // raw magnitude
    }
    __syncthreads();                                   // B5
    float addp = 0.f;
#pragma unroll
    for (int w = 0; w < TPB / 64; ++w) addp += (w < wid) ? fwt[w] : 0.f;
    const float ep = incf - rp + addp;

    // write-only inclusive prefixes from registers
    {
        float runp = ep, runm = em;
#pragma unroll
        for (int i = 0; i < EPT; ++i) {
            int li = seg + i;
            runp += pu[i];
            spu[li] = runp;
            runm += mg[i];
            smg[li] = runm;
        }
    }
    __syncthreads();                                   // B6

    float s1mf = 0.f, s2mf = 0.f, s1pf = 0.f, s2pf = 0.f;
    float* om = out + ((size_t)b * 2) * Ln + t0;
    float* op = out + ((size_t)b * 2 + 1) * Ln + t0;
    constexpr float INV_K = 1.0f / 301.0f;
#pragma unroll
    for (int j = 0; j < OPT; ++j) {
        int t = tid + j * TPB;
        int lt = t + 151;
        float am = (smg[lt + 150] - smg[lt - 151]) * INV_K;
        float fm = xm[j] - am;
        float ap = (spu[lt + 150] - spu[lt - 151]) * INV_K;
        float fp = xp[j] - ap;
        om[t] = fm;
        op[t] = fp;
        s1mf += fm; s2mf = __fmaf_rn(fm, fm, s2mf);
        s1pf += fp; s2pf = __fmaf_rn(fp, fp, s2pf);
    }
    double a0 = (double)s1mf, a1 = (double)s2mf, a2 = (double)s1pf, a3 = (double)s2pf;
#pragma unroll
    for (int o = 32; o > 0; o >>= 1) {
        a0 += __shfl_down(a0, o, 64);
        a1 += __shfl_down(a1, o, 64);
        a2 += __shfl_down(a2, o, 64);
        a3 += __shfl_down(a3, o, 64);
    }
    if (lane == 0) { rbuf[wid][0] = a0; rbuf[wid][1] = a1; rbuf[wid][2] = a2; rbuf[wid][3] = a3; }
    __syncthreads();
    if (tid == 0) {
        double t0d = 0, t1d = 0, t2d = 0, t3d = 0;
#pragma unroll
        for (int w = 0; w < TPB / 64; ++w) {
            t0d += rbuf[w][0]; t1d += rbuf[w][1]; t2d += rbuf[w][2]; t3d += rbuf[w][3];
        }
        float* p = PS + (size_t)(b * NC + c) * 4;
        p[0] = (float)t0d; p[1] = (float)t1d; p[2] = (float)t2d; p[3] = (float)t3d;
    }
}

// K2: per-row: fix last-150 phase outputs (right-pad windows) + row stats.
// One wave per row.
__global__ void k_post(const int* __restrict__ Ag, const int* __restrict__ Bg,
                       float* __restrict__ out, const float* __restrict__ PS,
                       float* __restrict__ ROW) {
    const int b = blockIdx.x;
    const int lane = threadIdx.x;           // 64 threads
    const int idx = b * NC;

    // row wrap offset at chunk NC-1 start: sum W_c over c<NC-1
    int w = (Bg[idx + lane] - Ag[idx + lane]);
    if (lane + 64 < NC - 1) w += (Bg[idx + 64 + lane] - Ag[idx + 64 + lane]);
#pragma unroll
    for (int o = 32; o > 0; o >>= 1) w += __shfl_down(w, o, 64);
    int O = __shfl(w, 0, 64);
    int aL = Ag[idx + NC - 1];
    float C = TWO_PI_F * (float)(O - aL);   // pu_true - pu_prov for last chunk

    constexpr float INV_K = 1.0f / 301.0f;
    float* op = out + ((size_t)b * 2 + 1) * Ln;
    double sd = 0.0, sd2 = 0.0;
#pragma unroll
    for (int k = 0; k < 3; ++k) {
        int j = lane + k * 64;
        if (j < 150) {
            int t = Ln - 150 + j;           // npad in window = j+1
            float delta = C * (float)(j + 1) * INV_K;
            float v = op[t];
            float nv = v + delta;
            op[t] = nv;
            sd += (double)delta;
            sd2 += (double)nv * (double)nv - (double)v * (double)v;
        }
    }

    // row stats: each lane sums 2 chunks, plus its own fix deltas
    const float* p1 = PS + (size_t)(idx + lane) * 4;
    const float* p2 = PS + (size_t)(idx + 64 + lane) * 4;
    double a0 = (double)p1[0] + (double)p2[0];
    double a1 = (double)p1[1] + (double)p2[1];
    double a2 = (double)p1[2] + (double)p2[2] + sd;
    double a3 = (double)p1[3] + (double)p2[3] + sd2;
#pragma unroll
    for (int o = 32; o > 0; o >>= 1) {
        a0 += __shfl_down(a0, o, 64);
        a1 += __shfl_down(a1, o, 64);
        a2 += __shfl_down(a2, o, 64);
        a3 += __shfl_down(a3, o, 64);
    }
    if (lane == 0) {
        double Ld = (double)Ln;
        double mm = a0 / Ld;
        double vm = (a1 - a0 * a0 / Ld) / (Ld - 1.0); vm = vm > 0 ? vm : 0;
        double mp = a2 / Ld;
        double vp = (a3 - a2 * a2 / Ld) / (Ld - 1.0); vp = vp > 0 ? vp : 0;
        float* r = ROW + b * 4;
        r[0] = (float)mm;
        r[1] = (float)(1.0 / (sqrt(vm) + 1e-5));
        r[2] = (float)mp;
        r[3] = (float)(1.0 / (sqrt(vp) + 1e-5));
    }
}

// in-place normalize of d_out
__global__ __launch_bounds__(TPB) void k_norm(float* __restrict__ out,
                                              const float* __restrict__ ROW) {
    const size_t n4 = (size_t)Bn * 2 * Ln / 4;
    size_t stride = (size_t)gridDim.x * blockDim.x;
    for (size_t p4 = (size_t)blockIdx.x * blockDim.x + threadIdx.x; p4 < n4; p4 += stride) {
        size_t p = p4 * 4;
        int b = (int)(p >> 19);             // 2L = 2^19
        int sig = (int)((p >> 18) & 1);     // L = 2^18
        float mean = ROW[b * 4 + sig * 2];
        float scale = ROW[b * 4 + sig * 2 + 1];
        float4 v = reinterpret_cast<float4*>(out)[p4];
        v.x = (v.x - mean) * scale;
        v.y = (v.y - mean) * scale;
        v.z = (v.z - mean) * scale;
        v.w = (v.w - mean) * scale;
        reinterpret_cast<float4*>(out)[p4] = v;
    }
}

extern "C" void kernel_launch(void* const* d_in, const int* in_sizes, int n_in,
                              void* d_out, int out_size, void* d_ws, size_t ws_size,
                              hipStream_t stream) {
    const float* Ig = (const float*)d_in[0];
    const float* Qg = (const float*)d_in[1];
    float* out = (float*)d_out;
    char* ws = (char*)d_ws;
    int* Ag = (int*)ws;                                 // Bn*NC ints (32 KiB)
    int* Bg = (int*)(ws + 32768);                       // Bn*NC ints (32 KiB)
    float* PS = (float*)(ws + 65536);                   // Bn*NC*4 floats (128 KiB)
    float* ROW = (float*)(ws + 65536 + (size_t)Bn * NC * 4 * sizeof(float));

    dim3 grid(NC, Bn);
    hipLaunchKernelGGL(k_filt, grid, dim3(TPB), 0, stream, Ig, Qg, Ag, Bg, out, PS);
    hipLaunchKernelGGL(k_post, dim3(Bn), dim3(64), 0, stream, Ag, Bg, out, PS, ROW);
    hipLaunchKernelGGL(k_norm, dim3(2048), dim3(TPB), 0, stream, out, ROW);
}